// Round 1
// baseline (275.740 us; speedup 1.0000x reference)
//
#include <hip/hip_runtime.h>

// ts_cov: x[B=256, T=512, F=32] fp32 -> cov[B, S=508, C=496] fp32
// cov[b,s,c] = mean_{t in [s,s+5)} x_i x_j - mean(x_i) mean(x_j), pairs (i<j) row-major.
//
// Write-BW-bound: 258 MB output. Block = 128 threads handles (b, 8 windows).
// LDS stages 12 rows x 32 feats; each lane owns 4 pair-columns x all 8 windows
// via register sliding sums. Stores are coalesced float4 rows.

#define T_DIM 512
#define F_DIM 32
#define B_DIM 256
#define WIN 5
#define S_DIM (T_DIM - WIN + 1)          // 508
#define C_DIM (F_DIM * (F_DIM - 1) / 2)  // 496
#define NS 8                             // windows per block
#define NROW (NS + WIN - 1)              // 12 x-rows staged per block

__global__ __launch_bounds__(128) void ts_cov_kernel(const float* __restrict__ x,
                                                     float* __restrict__ out) {
    __shared__ float xs[NROW * F_DIM];   // 384 floats = 1.5 KB

    const int b   = blockIdx.y;
    const int s0  = blockIdx.x * NS;
    const int tid = threadIdx.x;

    // ---- Stage x[b, s0 : s0+NROW, :] into LDS (coalesced float4) ----
    const float4* xsrc = (const float4*)(x + ((size_t)b * T_DIM + s0) * F_DIM);
    const int avail_f4 = (min(NROW, T_DIM - s0) * F_DIM) / 4;  // valid float4s
    if (tid < NROW * F_DIM / 4) {                              // 96 float4s
        float4 v = (tid < avail_f4) ? xsrc[tid]
                                    : make_float4(0.f, 0.f, 0.f, 0.f);
        ((float4*)xs)[tid] = v;
    }
    __syncthreads();

    if (tid >= C_DIM / 4) return;        // 124 active lanes per block

    const int nw = min(NS, S_DIM - s0);  // windows actually stored (tail: 4)

    // Decode pair (i, j) for c = tid*4, then step j across the 4 pairs.
    int i = 0, cc = tid * 4;
    while (cc >= F_DIM - 1 - i) { cc -= F_DIM - 1 - i; ++i; }
    int j = i + 1 + cc;

    float covreg[4][NS];

    #pragma unroll
    for (int p = 0; p < 4; ++p) {
        float xi[NROW], xj[NROW], pr[NROW];
        #pragma unroll
        for (int t = 0; t < NROW; ++t) {
            xi[t] = xs[t * F_DIM + i];   // same-i lanes broadcast; else distinct banks
            xj[t] = xs[t * F_DIM + j];
            pr[t] = xi[t] * xj[t];
        }

        float Si = xi[0] + xi[1] + xi[2] + xi[3] + xi[4];
        float Sj = xj[0] + xj[1] + xj[2] + xj[3] + xj[4];
        float P  = pr[0] + pr[1] + pr[2] + pr[3] + pr[4];

        #pragma unroll
        for (int w = 0; w < NS; ++w) {
            covreg[p][w] = 0.2f * P - (0.2f * Si) * (0.2f * Sj);
            if (w + 1 < NS) {
                Si += xi[w + WIN] - xi[w];
                Sj += xj[w + WIN] - xj[w];
                P  += pr[w + WIN] - pr[w];
            }
        }

        // advance (i, j) to next pair column
        ++j;
        if (j == F_DIM) { ++i; j = i + 1; }
    }

    // ---- Coalesced float4 stores: one contiguous 1984 B row per window ----
    #pragma unroll
    for (int w = 0; w < NS; ++w) {
        if (w < nw) {
            float4 v = make_float4(covreg[0][w], covreg[1][w],
                                   covreg[2][w], covreg[3][w]);
            float4* orow = (float4*)(out + ((size_t)b * S_DIM + (s0 + w)) * C_DIM);
            orow[tid] = v;
        }
    }
}

extern "C" void kernel_launch(void* const* d_in, const int* in_sizes, int n_in,
                              void* d_out, int out_size, void* d_ws, size_t ws_size,
                              hipStream_t stream) {
    const float* x = (const float*)d_in[0];
    float* out     = (float*)d_out;

    dim3 grid((S_DIM + NS - 1) / NS, B_DIM);   // (64, 256)
    dim3 block(128);
    ts_cov_kernel<<<grid, block, 0, stream>>>(x, out);
}

// Round 2
// 271.418 us; speedup vs baseline: 1.0159x; 1.0159x over previous
//
#include <hip/hip_runtime.h>

// ts_cov: x[B=256, T=512, F=32] fp32 -> cov[B, S=508, C=496] fp32
// cov[b,s,c(i,j)] = mean_{t in [s,s+5)} x_i x_j - mean(x_i) mean(x_j), pairs i<j row-major.
//
// Write-BW-bound target (~258 MB out). Block = 128 threads handles (b, 16 windows).
// LDS holds x transposed: xt[f][t] (stride NROW=20) so each pair's series loads as
// 5x ds_read_b128. Each of 124 lanes owns 4 consecutive pair-columns and all 16
// windows via register sliding sums; stores are coalesced float4 rows.

#define T_DIM 512
#define F_DIM 32
#define B_DIM 256
#define WIN 5
#define S_DIM (T_DIM - WIN + 1)          // 508
#define C_DIM (F_DIM * (F_DIM - 1) / 2)  // 496
#define NS 16                            // windows per block
#define NROW (NS + WIN - 1)              // 20 x-rows staged per block

__global__ __launch_bounds__(128) void ts_cov_kernel(const float* __restrict__ x,
                                                     float* __restrict__ out) {
    __shared__ float xt[F_DIM * NROW];   // transposed: xt[f*NROW + t], 2560 B

    const int b   = blockIdx.y;
    const int s0  = blockIdx.x * NS;     // 0,16,...,496
    const int tid = threadIdx.x;

    // ---- Stage x[b, s0 : s0+NROW, :] into LDS, transposed ----
    const float4* xsrc = (const float4*)(x + ((size_t)b * T_DIM + s0) * F_DIM);
    const int nrow_avail = min(NROW, T_DIM - s0);          // 20, or 16 for last tile
    #pragma unroll
    for (int idx = tid; idx < NROW * F_DIM / 4; idx += 128) {  // 160 float4s
        const int t  = idx >> 3;                           // row within tile
        const int f4 = idx & 7;                            // float4 within row
        float4 v = (t < nrow_avail) ? xsrc[idx] : make_float4(0.f, 0.f, 0.f, 0.f);
        xt[(4 * f4 + 0) * NROW + t] = v.x;
        xt[(4 * f4 + 1) * NROW + t] = v.y;
        xt[(4 * f4 + 2) * NROW + t] = v.z;
        xt[(4 * f4 + 3) * NROW + t] = v.w;
    }
    __syncthreads();

    if (tid >= C_DIM / 4) return;        // 124 active lanes

    const int nw = min(NS, S_DIM - s0);  // 16, or 12 for last tile

    // Decode pair (i, j) for c = tid*4.
    int i = 0, cc = tid * 4;
    while (cc >= F_DIM - 1 - i) { cc -= F_DIM - 1 - i; ++i; }
    int j = i + 1 + cc;

    float covreg[4][NS];

    #pragma unroll
    for (int p = 0; p < 4; ++p) {
        float xi[NROW], xj[NROW], pr[NROW];
        const float4* pi4 = (const float4*)(xt + i * NROW);  // 16B-aligned (20*4 B rows)
        const float4* pj4 = (const float4*)(xt + j * NROW);
        #pragma unroll
        for (int k = 0; k < NROW / 4; ++k) {               // 5x ds_read_b128 each
            float4 a = pi4[k], c4 = pj4[k];
            xi[4 * k + 0] = a.x;  xi[4 * k + 1] = a.y;
            xi[4 * k + 2] = a.z;  xi[4 * k + 3] = a.w;
            xj[4 * k + 0] = c4.x; xj[4 * k + 1] = c4.y;
            xj[4 * k + 2] = c4.z; xj[4 * k + 3] = c4.w;
        }
        #pragma unroll
        for (int t = 0; t < NROW; ++t) pr[t] = xi[t] * xj[t];

        float Si = (xi[0] + xi[1]) + (xi[2] + xi[3]) + xi[4];
        float Sj = (xj[0] + xj[1]) + (xj[2] + xj[3]) + xj[4];
        float P  = (pr[0] + pr[1]) + (pr[2] + pr[3]) + pr[4];

        #pragma unroll
        for (int w = 0; w < NS; ++w) {
            covreg[p][w] = 0.2f * P - (0.2f * Si) * (0.2f * Sj);
            if (w + 1 < NS) {
                Si += xi[w + WIN] - xi[w];
                Sj += xj[w + WIN] - xj[w];
                P  += pr[w + WIN] - pr[w];
            }
        }

        ++j;
        if (j == F_DIM) { ++i; j = i + 1; }
    }

    // ---- Coalesced float4 stores: one contiguous 1984 B row per window ----
    float4* obase = (float4*)(out + ((size_t)b * S_DIM + s0) * C_DIM);
    #pragma unroll
    for (int w = 0; w < NS; ++w) {
        if (w < nw) {
            float4 v = make_float4(covreg[0][w], covreg[1][w],
                                   covreg[2][w], covreg[3][w]);
            obase[(size_t)w * (C_DIM / 4) + tid] = v;
        }
    }
}

extern "C" void kernel_launch(void* const* d_in, const int* in_sizes, int n_in,
                              void* d_out, int out_size, void* d_ws, size_t ws_size,
                              hipStream_t stream) {
    const float* x = (const float*)d_in[0];
    float* out     = (float*)d_out;

    dim3 grid((S_DIM + NS - 1) / NS, B_DIM);   // (32, 256)
    dim3 block(128);
    ts_cov_kernel<<<grid, block, 0, stream>>>(x, out);
}